// Round 8
// baseline (166.242 us; speedup 1.0000x reference)
//
#include <hip/hip_runtime.h>

#define BB 4
#define SS 1024
#define DD 1024
#define HH 16
#define DKK 64
#define MM (BB*SS)   // 4096

typedef __bf16 bf16;
typedef __bf16 bf16x8 __attribute__((ext_vector_type(8)));
typedef float f32x4 __attribute__((ext_vector_type(4)));
typedef float f32x16 __attribute__((ext_vector_type(16)));

__device__ __forceinline__ f32x4 mfma16(bf16x8 a, bf16x8 b, f32x4 c) {
  return __builtin_amdgcn_mfma_f32_16x16x32_bf16(a, b, c, 0, 0, 0);
}
__device__ __forceinline__ f32x16 mfma32(bf16x8 a, bf16x8 b, f32x16 c) {
  return __builtin_amdgcn_mfma_f32_32x32x16_bf16(a, b, c, 0, 0, 0);
}
__device__ __forceinline__ float fexp2(float x) {
  return __builtin_amdgcn_exp2f(x);
}
__device__ __forceinline__ void gld_lds16(const bf16* g, bf16* l) {
  __builtin_amdgcn_global_load_lds(
      (const __attribute__((address_space(1))) void*)g,
      (__attribute__((address_space(3))) void*)l, 16, 0, 0);
}

// ---------------- fp32 -> bf16 convert (7 tensors) ----------------
__global__ __launch_bounds__(256)
void k_cvt7(const float* __restrict__ s0, const float* __restrict__ s1,
            const float* __restrict__ s2, const float* __restrict__ s3,
            const float* __restrict__ s4, const float* __restrict__ s5,
            const float* __restrict__ s6,
            bf16* __restrict__ d0, bf16* __restrict__ d1, bf16* __restrict__ d2,
            bf16* __restrict__ d3, bf16* __restrict__ d4, bf16* __restrict__ d5,
            bf16* __restrict__ d6) {
  const int t = blockIdx.y;
  const float* s = (t == 0) ? s0 : (t == 1) ? s1 : (t == 2) ? s2
                 : (t == 3) ? s3 : (t == 4) ? s4 : (t == 5) ? s5 : s6;
  bf16* d = (t == 0) ? d0 : (t == 1) ? d1 : (t == 2) ? d2
          : (t == 3) ? d3 : (t == 4) ? d4 : (t == 5) ? d5 : d6;
  const int n = (t < 3) ? (MM * DD) : (DD * DD);
  const int i0 = (blockIdx.x * 256 + threadIdx.x) * 8;
  if (i0 >= n) return;
  const f32x4 a = *(const f32x4*)(s + i0);
  const f32x4 b = *(const f32x4*)(s + i0 + 4);
  bf16x8 o;
#pragma unroll
  for (int j = 0; j < 4; ++j) { o[j] = (bf16)a[j]; o[4 + j] = (bf16)b[j]; }
  *(bf16x8*)(d + i0) = o;
}

// ---------------- mask -> bitmask ----------------
__global__ __launch_bounds__(256) void k_mask_bits(const int* __restrict__ mask,
                                                   unsigned* __restrict__ bits) {
  const int row = blockIdx.x;
  const int tid = threadIdx.x;
  const int lane = tid & 63, wv = tid >> 6;
#pragma unroll
  for (int it = 0; it < 4; ++it) {
    const int base = it * 256 + wv * 64;
    const int col = base + lane;
    unsigned long long bal = __ballot(mask[(size_t)row * SS + col] != 0);
    if (lane == 0) {
      bits[(size_t)row * 32 + (base >> 5)] = (unsigned)bal;
      bits[(size_t)row * 32 + (base >> 5) + 1] = (unsigned)(bal >> 32);
    }
  }
}

// ---------------- V transpose: Vb[B*S][D] -> Vt[B][H][64][S] ----------------
__global__ __launch_bounds__(256)
void k_vt(const bf16* __restrict__ V, bf16* __restrict__ Vt) {
  __shared__ bf16 t[64 * 65];
  const int st = blockIdx.x, h = blockIdx.y, b = blockIdx.z;
  const int row = threadIdx.x >> 3;        // 0..31
  const int c0 = (threadIdx.x & 7) * 8;
#pragma unroll
  for (int half = 0; half < 2; ++half) {
    const int s = row + half * 32;
    bf16x8 v = *(const bf16x8*)(V + (size_t)(b * SS + st * 64 + s) * DD + h * 64 + c0);
#pragma unroll
    for (int j = 0; j < 8; ++j) t[s * 65 + c0 + j] = v[j];
  }
  __syncthreads();
#pragma unroll
  for (int half = 0; half < 2; ++half) {
    const int d = row + half * 32;
    bf16x8 o;
#pragma unroll
    for (int j = 0; j < 8; ++j) o[j] = t[(c0 + j) * 65 + d];
    *(bf16x8*)(Vt + (size_t)((b * HH + h) * 64 + d) * SS + st * 64 + c0) = o;
  }
}

// Q pre-scaled by 1/sqrt(dk) * log2(e): attention runs in exp2 domain.
#define QSCALE 0.1803368801111204f

// ---------------- legacy GEMM (fallback when ws too small) ----------------
template<int AF32, int CF32>
__device__ __forceinline__ void gemm_body(const void* __restrict__ Ap,
                                          const float* __restrict__ Wp,
                                          void* __restrict__ Cp,
                                          int Mtot, int N, int K, int blk,
                                          float oscale) {
  __shared__ bf16 Al[128 * 40];
  __shared__ bf16 Bl[128 * 40];
  const int tid = threadIdx.x;
  const int lane = tid & 63;
  const int l15 = lane & 15, l4 = lane >> 4;
  const int wv = tid >> 6;
  const int nbm = Mtot >> 7;
  const int bm = blk % nbm, bn = blk / nbm;
  const size_t m0 = (size_t)bm << 7, n0 = (size_t)bn << 7;
  const int wr = (wv >> 1) << 6, wc = (wv & 1) << 6;
  const int srow = tid >> 2, scol = (tid & 3) << 3;

  f32x4 acc[4][4];
#pragma unroll
  for (int i = 0; i < 4; ++i)
#pragma unroll
    for (int j = 0; j < 4; ++j) acc[i][j] = f32x4{0.f, 0.f, 0.f, 0.f};

  for (int k0 = 0; k0 < K; k0 += 32) {
#pragma unroll
    for (int c = 0; c < 2; ++c) {
      const int row = (c << 6) + srow;
      bf16x8 av;
      if (AF32) {
        const float* s = (const float*)Ap + (m0 + row) * (size_t)K + k0 + scol;
        f32x4 v0 = *(const f32x4*)s;
        f32x4 v1 = *(const f32x4*)(s + 4);
#pragma unroll
        for (int j = 0; j < 4; ++j) { av[j] = (bf16)v0[j]; av[4 + j] = (bf16)v1[j]; }
      } else {
        av = *(const bf16x8*)((const bf16*)Ap + (m0 + row) * (size_t)K + k0 + scol);
      }
      *(bf16x8*)&Al[row * 40 + scol] = av;

      const float* ws_ = Wp + (n0 + row) * (size_t)K + k0 + scol;
      f32x4 w0 = *(const f32x4*)ws_;
      f32x4 w1 = *(const f32x4*)(ws_ + 4);
      bf16x8 wv8;
#pragma unroll
      for (int j = 0; j < 4; ++j) { wv8[j] = (bf16)w0[j]; wv8[4 + j] = (bf16)w1[j]; }
      *(bf16x8*)&Bl[row * 40 + scol] = wv8;
    }
    __syncthreads();

    bf16x8 af[4], bfv[4];
#pragma unroll
    for (int t = 0; t < 4; ++t) {
      af[t]  = *(const bf16x8*)&Al[(wr + t * 16 + l15) * 40 + l4 * 8];
      bfv[t] = *(const bf16x8*)&Bl[(wc + t * 16 + l15) * 40 + l4 * 8];
    }
    __builtin_amdgcn_s_setprio(1);
#pragma unroll
    for (int mt = 0; mt < 4; ++mt)
#pragma unroll
      for (int nt = 0; nt < 4; ++nt)
        acc[mt][nt] = mfma16(af[mt], bfv[nt], acc[mt][nt]);
    __builtin_amdgcn_s_setprio(0);
    __syncthreads();
  }

#pragma unroll
  for (int mt = 0; mt < 4; ++mt)
#pragma unroll
    for (int nt = 0; nt < 4; ++nt)
#pragma unroll
      for (int r = 0; r < 4; ++r) {
        const size_t row = m0 + wr + mt * 16 + l4 * 4 + r;
        const size_t col = n0 + wc + nt * 16 + l15;
        if (CF32) ((float*)Cp)[row * N + col] = acc[mt][nt][r];
        else      ((bf16*)Cp)[row * N + col] = (bf16)(acc[mt][nt][r] * oscale);
      }
}

__global__ __launch_bounds__(256)
void k_gemm_qkv(const float* __restrict__ A0, const float* __restrict__ A1,
                const float* __restrict__ A2, const float* __restrict__ W0,
                const float* __restrict__ W1, const float* __restrict__ W2,
                bf16* __restrict__ C0, bf16* __restrict__ C1, bf16* __restrict__ C2) {
  const int z = blockIdx.z;
  const float* A = (z == 0) ? A0 : (z == 1) ? A1 : A2;
  const float* W = (z == 0) ? W0 : (z == 1) ? W1 : W2;
  bf16* C = (z == 0) ? C0 : (z == 1) ? C1 : C2;
  const float sc = (z == 0) ? QSCALE : 1.0f;
  gemm_body<1, 0>(A, W, C, MM, DD, DD, blockIdx.x, sc);
}

__global__ __launch_bounds__(256)
void k_gemm_out(const bf16* __restrict__ A, const float* __restrict__ W,
                float* __restrict__ C) {
  gemm_body<0, 1>(A, W, C, MM, DD, DD, blockIdx.x, 1.0f);
}

// ---------------- bf16 GEMM with global_load_lds (m97 structure) ----------
__global__ __launch_bounds__(256)
void k_gemm_qkv_b16(const bf16* __restrict__ A0, const bf16* __restrict__ A1,
                    const bf16* __restrict__ A2, const bf16* __restrict__ W0,
                    const bf16* __restrict__ W1, const bf16* __restrict__ W2,
                    bf16* __restrict__ C0, bf16* __restrict__ C1,
                    bf16* __restrict__ C2) {
  __shared__ bf16 Al[128 * 32];
  __shared__ bf16 Bl[128 * 32];
  const int z = blockIdx.z;
  const bf16* A = (z == 0) ? A0 : (z == 1) ? A1 : A2;
  const bf16* W = (z == 0) ? W0 : (z == 1) ? W1 : W2;
  bf16* C = (z == 0) ? C0 : (z == 1) ? C1 : C2;
  const float oscale = (z == 0) ? QSCALE : 1.0f;

  const int tid = threadIdx.x, lane = tid & 63, w = tid >> 6;
  const int l15 = lane & 15, l4 = lane >> 4;
  const int bm = blockIdx.x & 31, bn = blockIdx.x >> 5;
  const size_t m0 = (size_t)bm << 7, n0 = (size_t)bn << 7;
  const int wr = (w >> 1) << 6, wc = (w & 1) << 6;
  const int srow = w * 32 + (lane >> 2);
  const int scol = (lane & 3) << 3;

  f32x4 acc[4][4];
#pragma unroll
  for (int i = 0; i < 4; ++i)
#pragma unroll
    for (int j = 0; j < 4; ++j) acc[i][j] = f32x4{0.f, 0.f, 0.f, 0.f};

  for (int k0 = 0; k0 < DD; k0 += 32) {
    const bf16* ga = A + (m0 + srow) * (size_t)DD + k0 + scol;
    const bf16* gb = W + (n0 + srow) * (size_t)DD + k0 + scol;
    gld_lds16(ga,            &Al[(w * 32) * 32]);
    gld_lds16(ga + 16 * DD,  &Al[(w * 32 + 16) * 32]);
    gld_lds16(gb,            &Bl[(w * 32) * 32]);
    gld_lds16(gb + 16 * DD,  &Bl[(w * 32 + 16) * 32]);
    __syncthreads();

    bf16x8 af[4], bfv[4];
#pragma unroll
    for (int t = 0; t < 4; ++t) {
      af[t]  = *(const bf16x8*)&Al[(wr + t * 16 + l15) * 32 + l4 * 8];
      bfv[t] = *(const bf16x8*)&Bl[(wc + t * 16 + l15) * 32 + l4 * 8];
    }
#pragma unroll
    for (int mt = 0; mt < 4; ++mt)
#pragma unroll
      for (int nt = 0; nt < 4; ++nt)
        acc[mt][nt] = mfma16(af[mt], bfv[nt], acc[mt][nt]);
    __syncthreads();
  }

#pragma unroll
  for (int mt = 0; mt < 4; ++mt)
#pragma unroll
    for (int nt = 0; nt < 4; ++nt)
#pragma unroll
      for (int r = 0; r < 4; ++r) {
        const size_t row = m0 + wr + mt * 16 + l4 * 4 + r;
        const size_t col = n0 + wc + nt * 16 + l15;
        C[row * DD + col] = (bf16)(acc[mt][nt][r] * oscale);
      }
}

__global__ __launch_bounds__(256)
void k_gemm_out_b16(const bf16* __restrict__ A, const bf16* __restrict__ W,
                    float* __restrict__ C) {
  __shared__ bf16 Al[128 * 32];
  __shared__ bf16 Bl[128 * 32];
  const int tid = threadIdx.x, lane = tid & 63, w = tid >> 6;
  const int l15 = lane & 15, l4 = lane >> 4;
  const int bm = blockIdx.x & 31, bn = blockIdx.x >> 5;
  const size_t m0 = (size_t)bm << 7, n0 = (size_t)bn << 7;
  const int wr = (w >> 1) << 6, wc = (w & 1) << 6;
  const int srow = w * 32 + (lane >> 2);
  const int scol = (lane & 3) << 3;

  f32x4 acc[4][4];
#pragma unroll
  for (int i = 0; i < 4; ++i)
#pragma unroll
    for (int j = 0; j < 4; ++j) acc[i][j] = f32x4{0.f, 0.f, 0.f, 0.f};

  for (int k0 = 0; k0 < DD; k0 += 32) {
    const bf16* ga = A + (m0 + srow) * (size_t)DD + k0 + scol;
    const bf16* gb = W + (n0 + srow) * (size_t)DD + k0 + scol;
    gld_lds16(ga,            &Al[(w * 32) * 32]);
    gld_lds16(ga + 16 * DD,  &Al[(w * 32 + 16) * 32]);
    gld_lds16(gb,            &Bl[(w * 32) * 32]);
    gld_lds16(gb + 16 * DD,  &Bl[(w * 32 + 16) * 32]);
    __syncthreads();

    bf16x8 af[4], bfv[4];
#pragma unroll
    for (int t = 0; t < 4; ++t) {
      af[t]  = *(const bf16x8*)&Al[(wr + t * 16 + l15) * 32 + l4 * 8];
      bfv[t] = *(const bf16x8*)&Bl[(wc + t * 16 + l15) * 32 + l4 * 8];
    }
#pragma unroll
    for (int mt = 0; mt < 4; ++mt)
#pragma unroll
      for (int nt = 0; nt < 4; ++nt)
        acc[mt][nt] = mfma16(af[mt], bfv[nt], acc[mt][nt]);
    __syncthreads();
  }

#pragma unroll
  for (int mt = 0; mt < 4; ++mt)
#pragma unroll
    for (int nt = 0; nt < 4; ++nt)
#pragma unroll
      for (int r = 0; r < 4; ++r) {
        const size_t row = m0 + wr + mt * 16 + l4 * 4 + r;
        const size_t col = n0 + wc + nt * 16 + l15;
        C[row * DD + col] = acc[mt][nt][r];
      }
}

// ------- flash attention: 32x32 MFMA, split-kv, V^T direct from global -----
// Block = 32 q rows, 4 waves each own a 256-kv quarter, KVBLK=32/iter.
// No LDS / no barriers in the main loop; V^T pre-transposed (k_vt), K and V^T
// fragments read straight from global (L2-resident, XCD-swizzled locality).
__global__ __launch_bounds__(256)
void k_attn(const bf16* __restrict__ Qw, const bf16* __restrict__ Kw,
            const bf16* __restrict__ Vt, const unsigned* __restrict__ mb,
            bf16* __restrict__ Xw) {
  __shared__ struct { float o[32 * 66]; float ml[4][2][32];
                      float inv[32]; float mst[32]; } sh;   // 9728 B
  const int tid = threadIdx.x, lane = tid & 63, w = tid >> 6;
  const int l31 = lane & 31, hi = lane >> 5;
  const unsigned bid = blockIdx.x;
  const unsigned wg = (bid & 7) * 256 + (bid >> 3);  // XCD chunk swizzle
  const int bh = wg >> 5, qt = wg & 31;
  const int h = bh & 15, b = bh >> 4;
  const int q0 = qt * 32;

  bf16x8 qf[4];
  {
    const bf16* Qb = Qw + (size_t)(b * SS + q0 + l31) * DD + h * 64 + hi * 8;
#pragma unroll
    for (int kt = 0; kt < 4; ++kt) qf[kt] = *(const bf16x8*)(Qb + kt * 16);
  }
  const bf16* Kb = Kw + (size_t)(b * SS) * DD + h * 64 + hi * 8;
  const bf16* Vtb = Vt + (size_t)(b * HH + h) * 64 * SS;   // [64][S]
  const unsigned* mrow = mb + (size_t)(b * SS + q0 + l31) * 32 + w * 8;

  f32x16 acco[2];
#pragma unroll
  for (int dt = 0; dt < 2; ++dt)
#pragma unroll
    for (int r = 0; r < 16; ++r) acco[dt][r] = 0.f;
  float mx = -3e38f, ssum = 0.f;
  const int kvw = w << 8;

  for (int it = 0; it < 8; ++it) {
    const int kv0 = kvw + it * 32;
    // K fragments (A operand) + V^T fragments (B operand) — issue all early
    bf16x8 kf[4];
    {
      const bf16* kp = Kb + (size_t)(kv0 + l31) * DD;
#pragma unroll
      for (int kt = 0; kt < 4; ++kt) kf[kt] = *(const bf16x8*)(kp + kt * 16);
    }
    bf16x8 vf[2][2];
#pragma unroll
    for (int dt = 0; dt < 2; ++dt) {
      const bf16* vp = Vtb + (size_t)(dt * 32 + l31) * SS + kv0 + hi * 8;
      vf[dt][0] = *(const bf16x8*)vp;
      vf[dt][1] = *(const bf16x8*)(vp + 16);
    }
    const unsigned mw = mrow[it];

    // swapped QK^T: S[kv][q], q = l31 per lane
    f32x16 s;
#pragma unroll
    for (int r = 0; r < 16; ++r) s[r] = 0.f;
    __builtin_amdgcn_s_setprio(1);
#pragma unroll
    for (int kt = 0; kt < 4; ++kt) s = mfma32(kf[kt], qf[kt], s);
    __builtin_amdgcn_s_setprio(0);

    float p[16];
#pragma unroll
    for (int r = 0; r < 16; ++r) {
      const int pos = (r & 3) + 8 * (r >> 2) + 4 * hi;
      p[r] = ((mw >> pos) & 1) ? s[r] : -1e9f;
    }
    // tree max
    float t0 = fmaxf(p[0], p[1]),  t1 = fmaxf(p[2], p[3]);
    float t2 = fmaxf(p[4], p[5]),  t3 = fmaxf(p[6], p[7]);
    float t4 = fmaxf(p[8], p[9]),  t5 = fmaxf(p[10], p[11]);
    float t6 = fmaxf(p[12], p[13]), t7 = fmaxf(p[14], p[15]);
    float rm = fmaxf(fmaxf(fmaxf(t0, t1), fmaxf(t2, t3)),
                     fmaxf(fmaxf(t4, t5), fmaxf(t6, t7)));
    rm = fmaxf(rm, __shfl_xor(rm, 32));
    if (!__all(rm <= mx + 8.0f)) {            // defer-max (T13)
      const float mn = fmaxf(mx, rm);
      const float scal = fexp2(mx - mn);
      mx = mn; ssum *= scal;
      float sr[16];
#pragma unroll
      for (int r = 0; r < 16; ++r)
        sr[r] = __shfl(scal, (r & 3) + 8 * (r >> 2) + 4 * hi);
#pragma unroll
      for (int dt = 0; dt < 2; ++dt)
#pragma unroll
        for (int r = 0; r < 16; ++r) acco[dt][r] *= sr[r];
    }
#pragma unroll
    for (int r = 0; r < 16; ++r) p[r] = fexp2(p[r] - mx);
    {
      float a0 = (p[0] + p[1]) + (p[2] + p[3]);
      float a1 = (p[4] + p[5]) + (p[6] + p[7]);
      float a2 = (p[8] + p[9]) + (p[10] + p[11]);
      float a3 = (p[12] + p[13]) + (p[14] + p[15]);
      ssum += (a0 + a1) + (a2 + a3);
    }

    // pack to bf16 pairs; dword i = kv pair {K(2i), K(2i)+1} (+4hi)
    int dpk[8];
#pragma unroll
    for (int i = 0; i < 8; ++i) {
      union { bf16 hh[2]; int v; } u;
      u.hh[0] = (bf16)p[2 * i]; u.hh[1] = (bf16)p[2 * i + 1];
      dpk[i] = u.v;
    }
    // XOR-32 exchange: partner holds the other half of each 16-kv k-tile
    const int sa = hi ? dpk[0] : dpk[2], sb = hi ? dpk[1] : dpk[3];
    const int sc_ = hi ? dpk[4] : dpk[6], sd = hi ? dpk[5] : dpk[7];
    const int ra = __shfl_xor(sa, 32), rb = __shfl_xor(sb, 32);
    const int rc = __shfl_xor(sc_, 32), rd = __shfl_xor(sd, 32);
    union { bf16x8 v; int q[4]; } pa0, pa1;
    pa0.q[0] = hi ? ra : dpk[0];  pa0.q[1] = hi ? rb : dpk[1];
    pa0.q[2] = hi ? dpk[2] : ra;  pa0.q[3] = hi ? dpk[3] : rb;
    pa1.q[0] = hi ? rc : dpk[4];  pa1.q[1] = hi ? rd : dpk[5];
    pa1.q[2] = hi ? dpk[6] : rc;  pa1.q[3] = hi ? dpk[7] : rd;

    // PV: O[q][d] += P * V
    __builtin_amdgcn_s_setprio(1);
#pragma unroll
    for (int dt = 0; dt < 2; ++dt) {
      acco[dt] = mfma32(pa0.v, vf[dt][0], acco[dt]);
      acco[dt] = mfma32(pa1.v, vf[dt][1], acco[dt]);
    }
    __builtin_amdgcn_s_setprio(0);
  }

  // ---- merge 4 kv-quarter partials ----
  ssum += __shfl_xor(ssum, 32);
  __syncthreads();
  if (hi == 0) { sh.ml[w][0][l31] = mx; sh.ml[w][1][l31] = ssum; }
  __syncthreads();
  if (w == 0 && hi == 0) {
    const float M0 = sh.ml[0][0][l31], M1 = sh.ml[1][0][l31];
    const float M2 = sh.ml[2][0][l31], M3 = sh.ml[3][0][l31];
    const float ms = fmaxf(fmaxf(M0, M1), fmaxf(M2, M3));
    const float ls = sh.ml[0][1][l31] * fexp2(M0 - ms)
                   + sh.ml[1][1][l31] * fexp2(M1 - ms)
                   + sh.ml[2][1][l31] * fexp2(M2 - ms)
                   + sh.ml[3][1][l31] * fexp2(M3 - ms);
    sh.inv[l31] = 1.0f / ls;
    sh.mst[l31] = ms;
  }
  __syncthreads();
  float fown[16];
#pragma unroll
  for (int r = 0; r < 16; ++r) {
    const int q_ = (r & 3) + 8 * (r >> 2) + 4 * hi;
    fown[r] = fexp2(sh.ml[w][0][q_] - sh.mst[q_]);
  }
  for (int rd2 = 0; rd2 < 4; ++rd2) {
    if (w == rd2) {
#pragma unroll
      for (int dt = 0; dt < 2; ++dt)
#pragma unroll
        for (int r = 0; r < 16; ++r) {
          const int q_ = (r & 3) + 8 * (r >> 2) + 4 * hi;
          const int o = q_ * 66 + dt * 32 + l31;
          const float val = acco[dt][r] * fown[r];
          if (rd2 == 0) sh.o[o] = val;
          else          sh.o[o] += val;
        }
    }
    __syncthreads();
  }
  {
    const int row = tid >> 3, c0 = (tid & 7) * 8;
    const float inv = sh.inv[row];
    const float* orow = &sh.o[row * 66 + c0];
    bf16x8 ov;
#pragma unroll
    for (int j = 0; j < 8; ++j) ov[j] = (bf16)(orow[j] * inv);
    *(bf16x8*)(Xw + (size_t)(b * SS + q0 + row) * DD + h * 64 + c0) = ov;
  }
}

// ---------------- launch ----------------
extern "C" void kernel_launch(void* const* d_in, const int* in_sizes, int n_in,
                              void* d_out, int out_size, void* d_ws, size_t ws_size,
                              hipStream_t stream) {
  const float* q32 = (const float*)d_in[0];
  const float* k32 = (const float*)d_in[1];
  const float* v32 = (const float*)d_in[2];
  const int* mask = (const int*)d_in[3];
  const float* Wq = (const float*)d_in[4];
  const float* Wk = (const float*)d_in[5];
  const float* Wv = (const float*)d_in[6];
  const float* Wo = (const float*)d_in[7];
  float* out = (float*)d_out;

  const size_t eAct = (size_t)MM * DD;
  const size_t eW = (size_t)DD * DD;

  bf16* Qb = (bf16*)d_ws;
  bf16* Kb = Qb + eAct;
  bf16* Vb = Kb + eAct;
  bf16* Xb = Vb + eAct;
  unsigned* mbits = (unsigned*)(Xb + eAct);
  bf16* Vtp = (bf16*)(mbits + (size_t)MM * 32);
  bf16* cvtBase = Vtp + eAct;
  bf16* Aq = cvtBase;
  bf16* Ak = Aq + eAct;
  bf16* Av = Ak + eAct;
  bf16* Wqb = Av + eAct;
  bf16* Wkb = Wqb + eW;
  bf16* Wvb = Wkb + eW;
  bf16* Wob = Wvb + eW;
  const size_t need = (size_t)((bf16*)(Wob + eW) - (bf16*)d_ws) * sizeof(bf16);

  k_mask_bits<<<BB * SS, 256, 0, stream>>>(mask, mbits);
  if (ws_size >= need) {
    k_cvt7<<<dim3(2048, 7), 256, 0, stream>>>(q32, k32, v32, Wq, Wk, Wv, Wo,
                                              Aq, Ak, Av, Wqb, Wkb, Wvb, Wob);
    k_gemm_qkv_b16<<<dim3(256, 1, 3), 256, 0, stream>>>(
        Aq, Ak, Av, Wqb, Wkb, Wvb, Qb, Kb, Vb);
    k_vt<<<dim3(16, 16, 4), 256, 0, stream>>>(Vb, Vtp);
    k_attn<<<BB * HH * (SS / 32), 256, 0, stream>>>(Qb, Kb, Vtp, mbits, Xb);
    k_gemm_out_b16<<<256, 256, 0, stream>>>(Xb, Wob, out);
  } else {
    k_gemm_qkv<<<dim3((MM / 128) * (DD / 128), 1, 3), 256, 0, stream>>>(
        q32, k32, v32, Wq, Wk, Wv, Qb, Kb, Vb);
    k_vt<<<dim3(16, 16, 4), 256, 0, stream>>>(Vb, Vtp);
    k_attn<<<BB * HH * (SS / 32), 256, 0, stream>>>(Qb, Kb, Vtp, mbits, Xb);
    k_gemm_out<<<(MM / 128) * (DD / 128), 256, 0, stream>>>(Xb, Wo, out);
  }
}

// Round 9
// 157.543 us; speedup vs baseline: 1.0552x; 1.0552x over previous
//
#include <hip/hip_runtime.h>

#define BB 4
#define SS 1024
#define DD 1024
#define HH 16
#define DKK 64
#define MM (BB*SS)   // 4096

typedef __bf16 bf16;
typedef __bf16 bf16x8 __attribute__((ext_vector_type(8)));
typedef float f32x4 __attribute__((ext_vector_type(4)));
typedef float f32x16 __attribute__((ext_vector_type(16)));

__device__ __forceinline__ f32x4 mfma16(bf16x8 a, bf16x8 b, f32x4 c) {
  return __builtin_amdgcn_mfma_f32_16x16x32_bf16(a, b, c, 0, 0, 0);
}
__device__ __forceinline__ f32x16 mfma32(bf16x8 a, bf16x8 b, f32x16 c) {
  return __builtin_amdgcn_mfma_f32_32x32x16_bf16(a, b, c, 0, 0, 0);
}
__device__ __forceinline__ float fexp2(float x) {
  return __builtin_amdgcn_exp2f(x);
}
__device__ __forceinline__ void gld_lds16(const bf16* g, bf16* l) {
  __builtin_amdgcn_global_load_lds(
      (const __attribute__((address_space(1))) void*)g,
      (__attribute__((address_space(3))) void*)l, 16, 0, 0);
}

// ---------------- fp32 -> bf16 convert (7 tensors) ----------------
__global__ __launch_bounds__(256)
void k_cvt7(const float* __restrict__ s0, const float* __restrict__ s1,
            const float* __restrict__ s2, const float* __restrict__ s3,
            const float* __restrict__ s4, const float* __restrict__ s5,
            const float* __restrict__ s6,
            bf16* __restrict__ d0, bf16* __restrict__ d1, bf16* __restrict__ d2,
            bf16* __restrict__ d3, bf16* __restrict__ d4, bf16* __restrict__ d5,
            bf16* __restrict__ d6) {
  const int t = blockIdx.y;
  const float* s = (t == 0) ? s0 : (t == 1) ? s1 : (t == 2) ? s2
                 : (t == 3) ? s3 : (t == 4) ? s4 : (t == 5) ? s5 : s6;
  bf16* d = (t == 0) ? d0 : (t == 1) ? d1 : (t == 2) ? d2
          : (t == 3) ? d3 : (t == 4) ? d4 : (t == 5) ? d5 : d6;
  const int n = (t < 3) ? (MM * DD) : (DD * DD);
  const int i0 = (blockIdx.x * 256 + threadIdx.x) * 8;
  if (i0 >= n) return;
  const f32x4 a = *(const f32x4*)(s + i0);
  const f32x4 b = *(const f32x4*)(s + i0 + 4);
  bf16x8 o;
#pragma unroll
  for (int j = 0; j < 4; ++j) { o[j] = (bf16)a[j]; o[4 + j] = (bf16)b[j]; }
  *(bf16x8*)(d + i0) = o;
}

// ---------------- mask -> bitmask ----------------
__global__ __launch_bounds__(256) void k_mask_bits(const int* __restrict__ mask,
                                                   unsigned* __restrict__ bits) {
  const int row = blockIdx.x;
  const int tid = threadIdx.x;
  const int lane = tid & 63, wv = tid >> 6;
#pragma unroll
  for (int it = 0; it < 4; ++it) {
    const int base = it * 256 + wv * 64;
    const int col = base + lane;
    unsigned long long bal = __ballot(mask[(size_t)row * SS + col] != 0);
    if (lane == 0) {
      bits[(size_t)row * 32 + (base >> 5)] = (unsigned)bal;
      bits[(size_t)row * 32 + (base >> 5) + 1] = (unsigned)(bal >> 32);
    }
  }
}

// Q pre-scaled by 1/sqrt(dk) * log2(e): attention runs in exp2 domain.
#define QSCALE 0.1803368801111204f

// ---------------- legacy GEMM (fallback when ws too small) ----------------
template<int AF32, int CF32>
__device__ __forceinline__ void gemm_body(const void* __restrict__ Ap,
                                          const float* __restrict__ Wp,
                                          void* __restrict__ Cp,
                                          int Mtot, int N, int K, int blk,
                                          float oscale) {
  __shared__ bf16 Al[128 * 40];
  __shared__ bf16 Bl[128 * 40];
  const int tid = threadIdx.x;
  const int lane = tid & 63;
  const int l15 = lane & 15, l4 = lane >> 4;
  const int wv = tid >> 6;
  const int nbm = Mtot >> 7;
  const int bm = blk % nbm, bn = blk / nbm;
  const size_t m0 = (size_t)bm << 7, n0 = (size_t)bn << 7;
  const int wr = (wv >> 1) << 6, wc = (wv & 1) << 6;
  const int srow = tid >> 2, scol = (tid & 3) << 3;

  f32x4 acc[4][4];
#pragma unroll
  for (int i = 0; i < 4; ++i)
#pragma unroll
    for (int j = 0; j < 4; ++j) acc[i][j] = f32x4{0.f, 0.f, 0.f, 0.f};

  for (int k0 = 0; k0 < K; k0 += 32) {
#pragma unroll
    for (int c = 0; c < 2; ++c) {
      const int row = (c << 6) + srow;
      bf16x8 av;
      if (AF32) {
        const float* s = (const float*)Ap + (m0 + row) * (size_t)K + k0 + scol;
        f32x4 v0 = *(const f32x4*)s;
        f32x4 v1 = *(const f32x4*)(s + 4);
#pragma unroll
        for (int j = 0; j < 4; ++j) { av[j] = (bf16)v0[j]; av[4 + j] = (bf16)v1[j]; }
      } else {
        av = *(const bf16x8*)((const bf16*)Ap + (m0 + row) * (size_t)K + k0 + scol);
      }
      *(bf16x8*)&Al[row * 40 + scol] = av;

      const float* ws_ = Wp + (n0 + row) * (size_t)K + k0 + scol;
      f32x4 w0 = *(const f32x4*)ws_;
      f32x4 w1 = *(const f32x4*)(ws_ + 4);
      bf16x8 wv8;
#pragma unroll
      for (int j = 0; j < 4; ++j) { wv8[j] = (bf16)w0[j]; wv8[4 + j] = (bf16)w1[j]; }
      *(bf16x8*)&Bl[row * 40 + scol] = wv8;
    }
    __syncthreads();

    bf16x8 af[4], bfv[4];
#pragma unroll
    for (int t = 0; t < 4; ++t) {
      af[t]  = *(const bf16x8*)&Al[(wr + t * 16 + l15) * 40 + l4 * 8];
      bfv[t] = *(const bf16x8*)&Bl[(wc + t * 16 + l15) * 40 + l4 * 8];
    }
    __builtin_amdgcn_s_setprio(1);
#pragma unroll
    for (int mt = 0; mt < 4; ++mt)
#pragma unroll
      for (int nt = 0; nt < 4; ++nt)
        acc[mt][nt] = mfma16(af[mt], bfv[nt], acc[mt][nt]);
    __builtin_amdgcn_s_setprio(0);
    __syncthreads();
  }

#pragma unroll
  for (int mt = 0; mt < 4; ++mt)
#pragma unroll
    for (int nt = 0; nt < 4; ++nt)
#pragma unroll
      for (int r = 0; r < 4; ++r) {
        const size_t row = m0 + wr + mt * 16 + l4 * 4 + r;
        const size_t col = n0 + wc + nt * 16 + l15;
        if (CF32) ((float*)Cp)[row * N + col] = acc[mt][nt][r];
        else      ((bf16*)Cp)[row * N + col] = (bf16)(acc[mt][nt][r] * oscale);
      }
}

__global__ __launch_bounds__(256)
void k_gemm_qkv(const float* __restrict__ A0, const float* __restrict__ A1,
                const float* __restrict__ A2, const float* __restrict__ W0,
                const float* __restrict__ W1, const float* __restrict__ W2,
                bf16* __restrict__ C0, bf16* __restrict__ C1, bf16* __restrict__ C2) {
  const int z = blockIdx.z;
  const float* A = (z == 0) ? A0 : (z == 1) ? A1 : A2;
  const float* W = (z == 0) ? W0 : (z == 1) ? W1 : W2;
  bf16* C = (z == 0) ? C0 : (z == 1) ? C1 : C2;
  const float sc = (z == 0) ? QSCALE : 1.0f;
  gemm_body<1, 0>(A, W, C, MM, DD, DD, blockIdx.x, sc);
}

__global__ __launch_bounds__(256)
void k_gemm_out(const bf16* __restrict__ A, const float* __restrict__ W,
                float* __restrict__ C) {
  gemm_body<0, 1>(A, W, C, MM, DD, DD, blockIdx.x, 1.0f);
}

// ---------------- bf16 GEMM with global_load_lds (m97 structure) ----------
__global__ __launch_bounds__(256)
void k_gemm_qkv_b16(const bf16* __restrict__ A0, const bf16* __restrict__ A1,
                    const bf16* __restrict__ A2, const bf16* __restrict__ W0,
                    const bf16* __restrict__ W1, const bf16* __restrict__ W2,
                    bf16* __restrict__ C0, bf16* __restrict__ C1,
                    bf16* __restrict__ C2) {
  __shared__ bf16 Al[128 * 32];
  __shared__ bf16 Bl[128 * 32];
  const int z = blockIdx.z;
  const bf16* A = (z == 0) ? A0 : (z == 1) ? A1 : A2;
  const bf16* W = (z == 0) ? W0 : (z == 1) ? W1 : W2;
  bf16* C = (z == 0) ? C0 : (z == 1) ? C1 : C2;
  const float oscale = (z == 0) ? QSCALE : 1.0f;

  const int tid = threadIdx.x, lane = tid & 63, w = tid >> 6;
  const int l15 = lane & 15, l4 = lane >> 4;
  const int bm = blockIdx.x & 31, bn = blockIdx.x >> 5;
  const size_t m0 = (size_t)bm << 7, n0 = (size_t)bn << 7;
  const int wr = (w >> 1) << 6, wc = (w & 1) << 6;
  const int srow = w * 32 + (lane >> 2);
  const int scol = (lane & 3) << 3;

  f32x4 acc[4][4];
#pragma unroll
  for (int i = 0; i < 4; ++i)
#pragma unroll
    for (int j = 0; j < 4; ++j) acc[i][j] = f32x4{0.f, 0.f, 0.f, 0.f};

  for (int k0 = 0; k0 < DD; k0 += 32) {
    const bf16* ga = A + (m0 + srow) * (size_t)DD + k0 + scol;
    const bf16* gb = W + (n0 + srow) * (size_t)DD + k0 + scol;
    gld_lds16(ga,            &Al[(w * 32) * 32]);
    gld_lds16(ga + 16 * DD,  &Al[(w * 32 + 16) * 32]);
    gld_lds16(gb,            &Bl[(w * 32) * 32]);
    gld_lds16(gb + 16 * DD,  &Bl[(w * 32 + 16) * 32]);
    __syncthreads();

    bf16x8 af[4], bfv[4];
#pragma unroll
    for (int t = 0; t < 4; ++t) {
      af[t]  = *(const bf16x8*)&Al[(wr + t * 16 + l15) * 32 + l4 * 8];
      bfv[t] = *(const bf16x8*)&Bl[(wc + t * 16 + l15) * 32 + l4 * 8];
    }
#pragma unroll
    for (int mt = 0; mt < 4; ++mt)
#pragma unroll
      for (int nt = 0; nt < 4; ++nt)
        acc[mt][nt] = mfma16(af[mt], bfv[nt], acc[mt][nt]);
    __syncthreads();
  }

#pragma unroll
  for (int mt = 0; mt < 4; ++mt)
#pragma unroll
    for (int nt = 0; nt < 4; ++nt)
#pragma unroll
      for (int r = 0; r < 4; ++r) {
        const size_t row = m0 + wr + mt * 16 + l4 * 4 + r;
        const size_t col = n0 + wc + nt * 16 + l15;
        C[row * DD + col] = (bf16)(acc[mt][nt][r] * oscale);
      }
}

__global__ __launch_bounds__(256)
void k_gemm_out_b16(const bf16* __restrict__ A, const bf16* __restrict__ W,
                    float* __restrict__ C) {
  __shared__ bf16 Al[128 * 32];
  __shared__ bf16 Bl[128 * 32];
  const int tid = threadIdx.x, lane = tid & 63, w = tid >> 6;
  const int l15 = lane & 15, l4 = lane >> 4;
  const int bm = blockIdx.x & 31, bn = blockIdx.x >> 5;
  const size_t m0 = (size_t)bm << 7, n0 = (size_t)bn << 7;
  const int wr = (w >> 1) << 6, wc = (w & 1) << 6;
  const int srow = w * 32 + (lane >> 2);
  const int scol = (lane & 3) << 3;

  f32x4 acc[4][4];
#pragma unroll
  for (int i = 0; i < 4; ++i)
#pragma unroll
    for (int j = 0; j < 4; ++j) acc[i][j] = f32x4{0.f, 0.f, 0.f, 0.f};

  for (int k0 = 0; k0 < DD; k0 += 32) {
    const bf16* ga = A + (m0 + srow) * (size_t)DD + k0 + scol;
    const bf16* gb = W + (n0 + srow) * (size_t)DD + k0 + scol;
    gld_lds16(ga,            &Al[(w * 32) * 32]);
    gld_lds16(ga + 16 * DD,  &Al[(w * 32 + 16) * 32]);
    gld_lds16(gb,            &Bl[(w * 32) * 32]);
    gld_lds16(gb + 16 * DD,  &Bl[(w * 32 + 16) * 32]);
    __syncthreads();

    bf16x8 af[4], bfv[4];
#pragma unroll
    for (int t = 0; t < 4; ++t) {
      af[t]  = *(const bf16x8*)&Al[(wr + t * 16 + l15) * 32 + l4 * 8];
      bfv[t] = *(const bf16x8*)&Bl[(wc + t * 16 + l15) * 32 + l4 * 8];
    }
#pragma unroll
    for (int mt = 0; mt < 4; ++mt)
#pragma unroll
      for (int nt = 0; nt < 4; ++nt)
        acc[mt][nt] = mfma16(af[mt], bfv[nt], acc[mt][nt]);
    __syncthreads();
  }

#pragma unroll
  for (int mt = 0; mt < 4; ++mt)
#pragma unroll
    for (int nt = 0; nt < 4; ++nt)
#pragma unroll
      for (int r = 0; r < 4; ++r) {
        const size_t row = m0 + wr + mt * 16 + l4 * 4 + r;
        const size_t col = n0 + wc + nt * 16 + l15;
        C[row * DD + col] = acc[mt][nt][r];
      }
}

// ------- flash attention v9: O^T form, gld_lds K/V dbuf, counted vmcnt ----
// Block = 64 q (2 qtiles of 32), 4 waves each own a 256-kv quarter,
// KVBLK=32/iter, 8 iters. K/V staged row-major [32][64] per wave via
// global_load_lds (dbuf, prefetch depth 1, s_waitcnt vmcnt(10)).
// K pre-swizzled chunk^(row&7) both sides. PV computes O^T = V^T * P^T:
// V A-frags = conflict-free column reads; P^T B-operand = XOR-32 routing.
__global__ __launch_bounds__(256)
void k_attn(const bf16* __restrict__ Qw, const bf16* __restrict__ Kw,
            const bf16* __restrict__ Vw, const unsigned* __restrict__ mb,
            bf16* __restrict__ Xw) {
  __shared__ union {
    struct { bf16 k[2][2048]; bf16 v[2][2048]; } st[4];     // 16 KiB / wave
    struct { float o[64 * 67]; float ml[4][2][64];
             float inv[64]; float mst[64]; } m;             // ~19.7 KiB
  } sh;
  const int tid = threadIdx.x, lane = tid & 63, w = tid >> 6;
  const int l31 = lane & 31, hi = lane >> 5;
  const unsigned bid = blockIdx.x;
  const unsigned wg = (bid & 7) * 128 + (bid >> 3);   // XCD swizzle (1024 = 8*128)
  const int bh = wg >> 4, qblk = wg & 15;
  const int h = bh & 15, b = bh >> 4;
  const int q0 = qblk * 64;

  // Q fragments (B operand): Q[q0 + qt*32 + l31][kt*16 + hi*8 + j]
  bf16x8 qf[2][4];
#pragma unroll
  for (int qt = 0; qt < 2; ++qt) {
    const bf16* Qb = Qw + (size_t)(b * SS + q0 + qt * 32 + l31) * DD + h * 64 + hi * 8;
#pragma unroll
    for (int kt = 0; kt < 4; ++kt) qf[qt][kt] = *(const bf16x8*)(Qb + kt * 16);
  }
  const bf16* Kg = Kw + (size_t)(b * SS) * DD + h * 64;
  const bf16* Vg = Vw + (size_t)(b * SS) * DD + h * 64;
  const unsigned* mrow0 = mb + (size_t)(b * SS + q0 + l31) * 32 + w * 8;
  const unsigned* mrow1 = mrow0 + 32 * 32;            // qt=1: +32 rows

  const int grow = lane >> 3;                         // staging row 0..7
  const int chV = (lane & 7) * 8;                     // bf16 units
  const int chK = ((lane & 7) ^ grow) * 8;            // pre-swizzled source
  const int kvw = w << 8;

  bf16* Kst[2] = { sh.st[w].k[0], sh.st[w].k[1] };
  bf16* Vst[2] = { sh.st[w].v[0], sh.st[w].v[1] };

#define AISSUE(T, BUF)                                                      \
  do {                                                                      \
    _Pragma("unroll")                                                       \
    for (int i_ = 0; i_ < 4; ++i_) {                                        \
      const size_t r_ = (size_t)(kvw + (T) * 32 + i_ * 8 + grow) * DD;      \
      gld_lds16(Kg + r_ + chK, Kst[BUF] + i_ * 512);                        \
      gld_lds16(Vg + r_ + chV, Vst[BUF] + i_ * 512);                        \
    }                                                                       \
  } while (0)

  f32x16 aco[2][2];
#pragma unroll
  for (int qt = 0; qt < 2; ++qt)
#pragma unroll
    for (int dt = 0; dt < 2; ++dt)
#pragma unroll
      for (int r = 0; r < 16; ++r) aco[qt][dt][r] = 0.f;
  float mx[2] = { -3e38f, -3e38f }, ssum[2] = { 0.f, 0.f };

  // prologue: batch 0 = 8 gld + 2 masks
  AISSUE(0, 0);
  unsigned mw0 = mrow0[0], mw1 = mrow1[0];

#pragma unroll
  for (int t = 0; t < 8; ++t) {
    const int cur = t & 1;
    unsigned nm0 = 0, nm1 = 0;
    if (t < 7) {
      AISSUE(t + 1, cur ^ 1);
      nm0 = mrow0[t + 1]; nm1 = mrow1[t + 1];
      asm volatile("s_waitcnt vmcnt(10)" ::: "memory");
    } else {
      asm volatile("s_waitcnt vmcnt(0)" ::: "memory");
    }
    __builtin_amdgcn_sched_barrier(0);

    // K fragments (A operand): K[kv=l31][d = kt*16+hi*8 ...], swizzled chunk
    const bf16* Kc = Kst[cur];
    bf16x8 kf[4];
#pragma unroll
    for (int kt = 0; kt < 4; ++kt)
      kf[kt] = *(const bf16x8*)&Kc[l31 * 64 + (((kt * 2 + hi) ^ (l31 & 7)) * 8)];
    // V A-fragments for PV (O^T): va[dt][s][j] = V[kv=s*16+hi*8+j][d=dt*32+l31]
    const bf16* Vc = Vst[cur];
    bf16x8 va[2][2];
#pragma unroll
    for (int dt = 0; dt < 2; ++dt)
#pragma unroll
      for (int s2 = 0; s2 < 2; ++s2) {
        bf16x8 tv;
#pragma unroll
        for (int j = 0; j < 8; ++j)
          tv[j] = Vc[(s2 * 16 + hi * 8 + j) * 64 + dt * 32 + l31];
        va[dt][s2] = tv;
      }

#pragma unroll
    for (int qt = 0; qt < 2; ++qt) {
      // swapped QK^T: S[kv][q=l31]
      f32x16 s;
#pragma unroll
      for (int r = 0; r < 16; ++r) s[r] = 0.f;
      __builtin_amdgcn_s_setprio(1);
#pragma unroll
      for (int kt = 0; kt < 4; ++kt) s = mfma32(kf[kt], qf[qt][kt], s);
      __builtin_amdgcn_s_setprio(0);

      const unsigned mw = qt ? mw1 : mw0;
      float p[16];
#pragma unroll
      for (int r = 0; r < 16; ++r) {
        const int pos = (r & 3) + 8 * (r >> 2) + 4 * hi;
        p[r] = ((mw >> pos) & 1) ? s[r] : -1e9f;
      }
      float t0 = fmaxf(p[0], p[1]),  t1 = fmaxf(p[2], p[3]);
      float t2 = fmaxf(p[4], p[5]),  t3 = fmaxf(p[6], p[7]);
      float t4 = fmaxf(p[8], p[9]),  t5 = fmaxf(p[10], p[11]);
      float t6 = fmaxf(p[12], p[13]), t7 = fmaxf(p[14], p[15]);
      float rm = fmaxf(fmaxf(fmaxf(t0, t1), fmaxf(t2, t3)),
                       fmaxf(fmaxf(t4, t5), fmaxf(t6, t7)));
      rm = fmaxf(rm, __shfl_xor(rm, 32));
      if (!__all(rm <= mx[qt] + 8.0f)) {           // defer-max (T13)
        const float mn = fmaxf(mx[qt], rm);
        const float scal = fexp2(mx[qt] - mn);     // per-lane scalar (q = l31)
        mx[qt] = mn; ssum[qt] *= scal;
#pragma unroll
        for (int dt = 0; dt < 2; ++dt)
#pragma unroll
          for (int r = 0; r < 16; ++r) aco[qt][dt][r] *= scal;
      }
#pragma unroll
      for (int r = 0; r < 16; ++r) p[r] = fexp2(p[r] - mx[qt]);
      {
        float a0 = (p[0] + p[1]) + (p[2] + p[3]);
        float a1 = (p[4] + p[5]) + (p[6] + p[7]);
        float a2 = (p[8] + p[9]) + (p[10] + p[11]);
        float a3 = (p[12] + p[13]) + (p[14] + p[15]);
        ssum[qt] += (a0 + a1) + (a2 + a3);
      }
      // pack + XOR-32 routing (verified r7): pa0 = kv 0..15, pa1 = kv 16..31
      int dpk[8];
#pragma unroll
      for (int i = 0; i < 8; ++i) {
        union { bf16 hh[2]; int v; } u;
        u.hh[0] = (bf16)p[2 * i]; u.hh[1] = (bf16)p[2 * i + 1];
        dpk[i] = u.v;
      }
      const int sa = hi ? dpk[0] : dpk[2], sb = hi ? dpk[1] : dpk[3];
      const int sc_ = hi ? dpk[4] : dpk[6], sd = hi ? dpk[5] : dpk[7];
      const int ra = __shfl_xor(sa, 32), rb = __shfl_xor(sb, 32);
      const int rc = __shfl_xor(sc_, 32), rd = __shfl_xor(sd, 32);
      union { bf16x8 v; int q[4]; } pa0, pa1;
      pa0.q[0] = hi ? ra : dpk[0];  pa0.q[1] = hi ? rb : dpk[1];
      pa0.q[2] = hi ? dpk[2] : ra;  pa0.q[3] = hi ? dpk[3] : rb;
      pa1.q[0] = hi ? rc : dpk[4];  pa1.q[1] = hi ? rd : dpk[5];
      pa1.q[2] = hi ? dpk[6] : rc;  pa1.q[3] = hi ? dpk[7] : rd;

      // PV (O^T): aco[qt][dt] += V^T * P^T
      __builtin_amdgcn_s_setprio(1);
#pragma unroll
      for (int dt = 0; dt < 2; ++dt) {
        aco[qt][dt] = mfma32(va[dt][0], pa0.v, aco[qt][dt]);
        aco[qt][dt] = mfma32(va[dt][1], pa1.v, aco[qt][dt]);
      }
      __builtin_amdgcn_s_setprio(0);
    }
    mw0 = nm0; mw1 = nm1;
  }
#undef AISSUE

  // ---- merge 4 kv-quarter partials (O^T in LDS) ----
#pragma unroll
  for (int qt = 0; qt < 2; ++qt) ssum[qt] += __shfl_xor(ssum[qt], 32);
  __syncthreads();                                  // stage buffers dead
  if (hi == 0) {
#pragma unroll
    for (int qt = 0; qt < 2; ++qt) {
      sh.m.ml[w][0][qt * 32 + l31] = mx[qt];
      sh.m.ml[w][1][qt * 32 + l31] = ssum[qt];
    }
  }
  __syncthreads();
  if (w == 0) {                                     // lane = q (64 q rows)
    const float M0 = sh.m.ml[0][0][lane], M1 = sh.m.ml[1][0][lane];
    const float M2 = sh.m.ml[2][0][lane], M3 = sh.m.ml[3][0][lane];
    const float ms = fmaxf(fmaxf(M0, M1), fmaxf(M2, M3));
    const float ls = sh.m.ml[0][1][lane] * fexp2(M0 - ms)
                   + sh.m.ml[1][1][lane] * fexp2(M1 - ms)
                   + sh.m.ml[2][1][lane] * fexp2(M2 - ms)
                   + sh.m.ml[3][1][lane] * fexp2(M3 - ms);
    sh.m.inv[lane] = 1.0f / ls;
    sh.m.mst[lane] = ms;
  }
  __syncthreads();
  float fown[2];
#pragma unroll
  for (int qt = 0; qt < 2; ++qt)
    fown[qt] = fexp2(sh.m.ml[w][0][qt * 32 + l31] - sh.m.mst[qt * 32 + l31]);
  for (int rd2 = 0; rd2 < 4; ++rd2) {
    if (w == rd2) {
#pragma unroll
      for (int qt = 0; qt < 2; ++qt)
#pragma unroll
        for (int dt = 0; dt < 2; ++dt)
#pragma unroll
          for (int r = 0; r < 16; ++r) {
            const int d = dt * 32 + (r & 3) + 8 * (r >> 2) + 4 * hi;
            const int o = d * 67 + qt * 32 + l31;
            const float val = aco[qt][dt][r] * fown[qt];
            if (rd2 == 0) sh.m.o[o] = val;
            else          sh.m.o[o] += val;
          }
    }
    __syncthreads();
  }
  {
    const int q = tid >> 2, c0 = (tid & 3) * 16;    // o is [d][q] (stride 67)
    const float inv = sh.m.inv[q];
    bf16x8 w0, w1;
#pragma unroll
    for (int j = 0; j < 8; ++j) {
      w0[j] = (bf16)(sh.m.o[(c0 + j) * 67 + q] * inv);
      w1[j] = (bf16)(sh.m.o[(c0 + 8 + j) * 67 + q] * inv);
    }
    bf16* xp = Xw + (size_t)(b * SS + q0 + q) * DD + h * 64 + c0;
    *(bf16x8*)xp = w0;
    *(bf16x8*)(xp + 8) = w1;
  }
}

// ---------------- launch ----------------
extern "C" void kernel_launch(void* const* d_in, const int* in_sizes, int n_in,
                              void* d_out, int out_size, void* d_ws, size_t ws_size,
                              hipStream_t stream) {
  const float* q32 = (const float*)d_in[0];
  const float* k32 = (const float*)d_in[1];
  const float* v32 = (const float*)d_in[2];
  const int* mask = (const int*)d_in[3];
  const float* Wq = (const float*)d_in[4];
  const float* Wk = (const float*)d_in[5];
  const float* Wv = (const float*)d_in[6];
  const float* Wo = (const float*)d_in[7];
  float* out = (float*)d_out;

  const size_t eAct = (size_t)MM * DD;
  const size_t eW = (size_t)DD * DD;

  bf16* Qb = (bf16*)d_ws;
  bf16* Kb = Qb + eAct;
  bf16* Vb = Kb + eAct;
  bf16* Xb = Vb + eAct;
  unsigned* mbits = (unsigned*)(Xb + eAct);
  bf16* cvtBase = (bf16*)(mbits + (size_t)MM * 32);
  bf16* Aq = cvtBase;
  bf16* Ak = Aq + eAct;
  bf16* Av = Ak + eAct;
  bf16* Wqb = Av + eAct;
  bf16* Wkb = Wqb + eW;
  bf16* Wvb = Wkb + eW;
  bf16* Wob = Wvb + eW;
  const size_t need = (size_t)((bf16*)(Wob + eW) - (bf16*)d_ws) * sizeof(bf16);

  k_mask_bits<<<BB * SS, 256, 0, stream>>>(mask, mbits);
  if (ws_size >= need) {
    k_cvt7<<<dim3(2048, 7), 256, 0, stream>>>(q32, k32, v32, Wq, Wk, Wv, Wo,
                                              Aq, Ak, Av, Wqb, Wkb, Wvb, Wob);
    k_gemm_qkv_b16<<<dim3(256, 1, 3), 256, 0, stream>>>(
        Aq, Ak, Av, Wqb, Wkb, Wvb, Qb, Kb, Vb);
    k_attn<<<BB * HH * (SS / 64), 256, 0, stream>>>(Qb, Kb, Vb, mbits, Xb);
    k_gemm_out_b16<<<256, 256, 0, stream>>>(Xb, Wob, out);
  } else {
    k_gemm_qkv<<<dim3((MM / 128) * (DD / 128), 1, 3), 256, 0, stream>>>(
        q32, k32, v32, Wq, Wk, Wv, Qb, Kb, Vb);
    k_attn<<<BB * HH * (SS / 64), 256, 0, stream>>>(Qb, Kb, Vb, mbits, Xb);
    k_gemm_out<<<(MM / 128) * (DD / 128), 256, 0, stream>>>(Xb, Wo, out);
  }
}

// Round 10
// 135.159 us; speedup vs baseline: 1.2300x; 1.1656x over previous
//
#include <hip/hip_runtime.h>

#define BB 4
#define SS 1024
#define DD 1024
#define HH 16
#define DKK 64
#define MM (BB*SS)   // 4096

typedef __bf16 bf16;
typedef __bf16 bf16x8 __attribute__((ext_vector_type(8)));
typedef float f32x4 __attribute__((ext_vector_type(4)));
typedef float f32x16 __attribute__((ext_vector_type(16)));

__device__ __forceinline__ f32x4 mfma16(bf16x8 a, bf16x8 b, f32x4 c) {
  return __builtin_amdgcn_mfma_f32_16x16x32_bf16(a, b, c, 0, 0, 0);
}
__device__ __forceinline__ f32x16 mfma32(bf16x8 a, bf16x8 b, f32x16 c) {
  return __builtin_amdgcn_mfma_f32_32x32x16_bf16(a, b, c, 0, 0, 0);
}
__device__ __forceinline__ float fexp2(float x) {
  return __builtin_amdgcn_exp2f(x);
}
__device__ __forceinline__ void gld_lds16(const bf16* g, bf16* l) {
  __builtin_amdgcn_global_load_lds(
      (const __attribute__((address_space(1))) void*)g,
      (__attribute__((address_space(3))) void*)l, 16, 0, 0);
}

// ---------------- fp32 -> bf16 convert (7 tensors) ----------------
__global__ __launch_bounds__(256)
void k_cvt7(const float* __restrict__ s0, const float* __restrict__ s1,
            const float* __restrict__ s2, const float* __restrict__ s3,
            const float* __restrict__ s4, const float* __restrict__ s5,
            const float* __restrict__ s6,
            bf16* __restrict__ d0, bf16* __restrict__ d1, bf16* __restrict__ d2,
            bf16* __restrict__ d3, bf16* __restrict__ d4, bf16* __restrict__ d5,
            bf16* __restrict__ d6) {
  const int t = blockIdx.y;
  const float* s = (t == 0) ? s0 : (t == 1) ? s1 : (t == 2) ? s2
                 : (t == 3) ? s3 : (t == 4) ? s4 : (t == 5) ? s5 : s6;
  bf16* d = (t == 0) ? d0 : (t == 1) ? d1 : (t == 2) ? d2
          : (t == 3) ? d3 : (t == 4) ? d4 : (t == 5) ? d5 : d6;
  const int n = (t < 3) ? (MM * DD) : (DD * DD);
  const int i0 = (blockIdx.x * 256 + threadIdx.x) * 8;
  if (i0 >= n) return;
  const f32x4 a = *(const f32x4*)(s + i0);
  const f32x4 b = *(const f32x4*)(s + i0 + 4);
  bf16x8 o;
#pragma unroll
  for (int j = 0; j < 4; ++j) { o[j] = (bf16)a[j]; o[4 + j] = (bf16)b[j]; }
  *(bf16x8*)(d + i0) = o;
}

// ---------------- mask -> bitmask ----------------
__global__ __launch_bounds__(256) void k_mask_bits(const int* __restrict__ mask,
                                                   unsigned* __restrict__ bits) {
  const int row = blockIdx.x;
  const int tid = threadIdx.x;
  const int lane = tid & 63, wv = tid >> 6;
#pragma unroll
  for (int it = 0; it < 4; ++it) {
    const int base = it * 256 + wv * 64;
    const int col = base + lane;
    unsigned long long bal = __ballot(mask[(size_t)row * SS + col] != 0);
    if (lane == 0) {
      bits[(size_t)row * 32 + (base >> 5)] = (unsigned)bal;
      bits[(size_t)row * 32 + (base >> 5) + 1] = (unsigned)(bal >> 32);
    }
  }
}

// Q pre-scaled by 1/sqrt(dk) * log2(e): attention runs in exp2 domain.
#define QSCALE 0.1803368801111204f

// ---------------- legacy GEMM (fallback when ws too small) ----------------
template<int AF32, int CF32>
__device__ __forceinline__ void gemm_body(const void* __restrict__ Ap,
                                          const float* __restrict__ Wp,
                                          void* __restrict__ Cp,
                                          int Mtot, int N, int K, int blk,
                                          float oscale) {
  __shared__ bf16 Al[128 * 40];
  __shared__ bf16 Bl[128 * 40];
  const int tid = threadIdx.x;
  const int lane = tid & 63;
  const int l15 = lane & 15, l4 = lane >> 4;
  const int wv = tid >> 6;
  const int nbm = Mtot >> 7;
  const int bm = blk % nbm, bn = blk / nbm;
  const size_t m0 = (size_t)bm << 7, n0 = (size_t)bn << 7;
  const int wr = (wv >> 1) << 6, wc = (wv & 1) << 6;
  const int srow = tid >> 2, scol = (tid & 3) << 3;

  f32x4 acc[4][4];
#pragma unroll
  for (int i = 0; i < 4; ++i)
#pragma unroll
    for (int j = 0; j < 4; ++j) acc[i][j] = f32x4{0.f, 0.f, 0.f, 0.f};

  for (int k0 = 0; k0 < K; k0 += 32) {
#pragma unroll
    for (int c = 0; c < 2; ++c) {
      const int row = (c << 6) + srow;
      bf16x8 av;
      if (AF32) {
        const float* s = (const float*)Ap + (m0 + row) * (size_t)K + k0 + scol;
        f32x4 v0 = *(const f32x4*)s;
        f32x4 v1 = *(const f32x4*)(s + 4);
#pragma unroll
        for (int j = 0; j < 4; ++j) { av[j] = (bf16)v0[j]; av[4 + j] = (bf16)v1[j]; }
      } else {
        av = *(const bf16x8*)((const bf16*)Ap + (m0 + row) * (size_t)K + k0 + scol);
      }
      *(bf16x8*)&Al[row * 40 + scol] = av;

      const float* ws_ = Wp + (n0 + row) * (size_t)K + k0 + scol;
      f32x4 w0 = *(const f32x4*)ws_;
      f32x4 w1 = *(const f32x4*)(ws_ + 4);
      bf16x8 wv8;
#pragma unroll
      for (int j = 0; j < 4; ++j) { wv8[j] = (bf16)w0[j]; wv8[4 + j] = (bf16)w1[j]; }
      *(bf16x8*)&Bl[row * 40 + scol] = wv8;
    }
    __syncthreads();

    bf16x8 af[4], bfv[4];
#pragma unroll
    for (int t = 0; t < 4; ++t) {
      af[t]  = *(const bf16x8*)&Al[(wr + t * 16 + l15) * 40 + l4 * 8];
      bfv[t] = *(const bf16x8*)&Bl[(wc + t * 16 + l15) * 40 + l4 * 8];
    }
    __builtin_amdgcn_s_setprio(1);
#pragma unroll
    for (int mt = 0; mt < 4; ++mt)
#pragma unroll
      for (int nt = 0; nt < 4; ++nt)
        acc[mt][nt] = mfma16(af[mt], bfv[nt], acc[mt][nt]);
    __builtin_amdgcn_s_setprio(0);
    __syncthreads();
  }

#pragma unroll
  for (int mt = 0; mt < 4; ++mt)
#pragma unroll
    for (int nt = 0; nt < 4; ++nt)
#pragma unroll
      for (int r = 0; r < 4; ++r) {
        const size_t row = m0 + wr + mt * 16 + l4 * 4 + r;
        const size_t col = n0 + wc + nt * 16 + l15;
        if (CF32) ((float*)Cp)[row * N + col] = acc[mt][nt][r];
        else      ((bf16*)Cp)[row * N + col] = (bf16)(acc[mt][nt][r] * oscale);
      }
}

__global__ __launch_bounds__(256)
void k_gemm_qkv(const float* __restrict__ A0, const float* __restrict__ A1,
                const float* __restrict__ A2, const float* __restrict__ W0,
                const float* __restrict__ W1, const float* __restrict__ W2,
                bf16* __restrict__ C0, bf16* __restrict__ C1, bf16* __restrict__ C2) {
  const int z = blockIdx.z;
  const float* A = (z == 0) ? A0 : (z == 1) ? A1 : A2;
  const float* W = (z == 0) ? W0 : (z == 1) ? W1 : W2;
  bf16* C = (z == 0) ? C0 : (z == 1) ? C1 : C2;
  const float sc = (z == 0) ? QSCALE : 1.0f;
  gemm_body<1, 0>(A, W, C, MM, DD, DD, blockIdx.x, sc);
}

__global__ __launch_bounds__(256)
void k_gemm_out(const bf16* __restrict__ A, const float* __restrict__ W,
                float* __restrict__ C) {
  gemm_body<0, 1>(A, W, C, MM, DD, DD, blockIdx.x, 1.0f);
}

// ---------------- bf16 GEMM with global_load_lds (m97 structure) ----------
__global__ __launch_bounds__(256)
void k_gemm_qkv_b16(const bf16* __restrict__ A0, const bf16* __restrict__ A1,
                    const bf16* __restrict__ A2, const bf16* __restrict__ W0,
                    const bf16* __restrict__ W1, const bf16* __restrict__ W2,
                    bf16* __restrict__ C0, bf16* __restrict__ C1,
                    bf16* __restrict__ C2) {
  __shared__ bf16 Al[128 * 32];
  __shared__ bf16 Bl[128 * 32];
  const int z = blockIdx.z;
  const bf16* A = (z == 0) ? A0 : (z == 1) ? A1 : A2;
  const bf16* W = (z == 0) ? W0 : (z == 1) ? W1 : W2;
  bf16* C = (z == 0) ? C0 : (z == 1) ? C1 : C2;
  const float oscale = (z == 0) ? QSCALE : 1.0f;

  const int tid = threadIdx.x, lane = tid & 63, w = tid >> 6;
  const int l15 = lane & 15, l4 = lane >> 4;
  const int bm = blockIdx.x & 31, bn = blockIdx.x >> 5;
  const size_t m0 = (size_t)bm << 7, n0 = (size_t)bn << 7;
  const int wr = (w >> 1) << 6, wc = (w & 1) << 6;
  const int srow = w * 32 + (lane >> 2);
  const int scol = (lane & 3) << 3;

  f32x4 acc[4][4];
#pragma unroll
  for (int i = 0; i < 4; ++i)
#pragma unroll
    for (int j = 0; j < 4; ++j) acc[i][j] = f32x4{0.f, 0.f, 0.f, 0.f};

  for (int k0 = 0; k0 < DD; k0 += 32) {
    const bf16* ga = A + (m0 + srow) * (size_t)DD + k0 + scol;
    const bf16* gb = W + (n0 + srow) * (size_t)DD + k0 + scol;
    gld_lds16(ga,            &Al[(w * 32) * 32]);
    gld_lds16(ga + 16 * DD,  &Al[(w * 32 + 16) * 32]);
    gld_lds16(gb,            &Bl[(w * 32) * 32]);
    gld_lds16(gb + 16 * DD,  &Bl[(w * 32 + 16) * 32]);
    __syncthreads();

    bf16x8 af[4], bfv[4];
#pragma unroll
    for (int t = 0; t < 4; ++t) {
      af[t]  = *(const bf16x8*)&Al[(wr + t * 16 + l15) * 32 + l4 * 8];
      bfv[t] = *(const bf16x8*)&Bl[(wc + t * 16 + l15) * 32 + l4 * 8];
    }
#pragma unroll
    for (int mt = 0; mt < 4; ++mt)
#pragma unroll
      for (int nt = 0; nt < 4; ++nt)
        acc[mt][nt] = mfma16(af[mt], bfv[nt], acc[mt][nt]);
    __syncthreads();
  }

#pragma unroll
  for (int mt = 0; mt < 4; ++mt)
#pragma unroll
    for (int nt = 0; nt < 4; ++nt)
#pragma unroll
      for (int r = 0; r < 4; ++r) {
        const size_t row = m0 + wr + mt * 16 + l4 * 4 + r;
        const size_t col = n0 + wc + nt * 16 + l15;
        C[row * DD + col] = (bf16)(acc[mt][nt][r] * oscale);
      }
}

__global__ __launch_bounds__(256)
void k_gemm_out_b16(const bf16* __restrict__ A, const bf16* __restrict__ W,
                    float* __restrict__ C) {
  __shared__ bf16 Al[128 * 32];
  __shared__ bf16 Bl[128 * 32];
  const int tid = threadIdx.x, lane = tid & 63, w = tid >> 6;
  const int l15 = lane & 15, l4 = lane >> 4;
  const int bm = blockIdx.x & 31, bn = blockIdx.x >> 5;
  const size_t m0 = (size_t)bm << 7, n0 = (size_t)bn << 7;
  const int wr = (w >> 1) << 6, wc = (w & 1) << 6;
  const int srow = w * 32 + (lane >> 2);
  const int scol = (lane & 3) << 3;

  f32x4 acc[4][4];
#pragma unroll
  for (int i = 0; i < 4; ++i)
#pragma unroll
    for (int j = 0; j < 4; ++j) acc[i][j] = f32x4{0.f, 0.f, 0.f, 0.f};

  for (int k0 = 0; k0 < DD; k0 += 32) {
    const bf16* ga = A + (m0 + srow) * (size_t)DD + k0 + scol;
    const bf16* gb = W + (n0 + srow) * (size_t)DD + k0 + scol;
    gld_lds16(ga,            &Al[(w * 32) * 32]);
    gld_lds16(ga + 16 * DD,  &Al[(w * 32 + 16) * 32]);
    gld_lds16(gb,            &Bl[(w * 32) * 32]);
    gld_lds16(gb + 16 * DD,  &Bl[(w * 32 + 16) * 32]);
    __syncthreads();

    bf16x8 af[4], bfv[4];
#pragma unroll
    for (int t = 0; t < 4; ++t) {
      af[t]  = *(const bf16x8*)&Al[(wr + t * 16 + l15) * 32 + l4 * 8];
      bfv[t] = *(const bf16x8*)&Bl[(wc + t * 16 + l15) * 32 + l4 * 8];
    }
#pragma unroll
    for (int mt = 0; mt < 4; ++mt)
#pragma unroll
      for (int nt = 0; nt < 4; ++nt)
        acc[mt][nt] = mfma16(af[mt], bfv[nt], acc[mt][nt]);
    __syncthreads();
  }

#pragma unroll
  for (int mt = 0; mt < 4; ++mt)
#pragma unroll
    for (int nt = 0; nt < 4; ++nt)
#pragma unroll
      for (int r = 0; r < 4; ++r) {
        const size_t row = m0 + wr + mt * 16 + l4 * 4 + r;
        const size_t col = n0 + wc + nt * 16 + l15;
        C[row * DD + col] = acc[mt][nt][r];
      }
}

// ------- flash attention v10: split-kv, V gld_lds single-buf, O^T PV -------
// Block = 64 q (2 qtiles of 32), 4 waves each own a 256-kv quarter,
// KVBLK=32/iter, 8 iters, ZERO barriers in main loop. V staged linear
// [32kv][64d] per-wave via 4x global_load_lds (4KB/wave); K fragments direct
// from global (L2-resident); PV computes O^T = V^T * P^T with XOR-32 routing.
__global__ __launch_bounds__(256)
void k_attn(const bf16* __restrict__ Qw, const bf16* __restrict__ Kw,
            const bf16* __restrict__ Vw, const unsigned* __restrict__ mb,
            bf16* __restrict__ Xw) {
  __shared__ union {
    bf16 v[4][2048];                                        // 16 KiB staging
    struct { float o[64 * 67]; float ml[4][2][64];
             float inv[64]; float mst[64]; } m;             // ~19.7 KiB merge
  } sh;
  const int tid = threadIdx.x, lane = tid & 63, w = tid >> 6;
  const int l31 = lane & 31, hi = lane >> 5;
  const unsigned bid = blockIdx.x;
  const unsigned wg = (bid & 7) * 128 + (bid >> 3);   // XCD swizzle (1024 = 8*128)
  const int bh = wg >> 4, qblk = wg & 15;
  const int h = bh & 15, b = bh >> 4;
  const int q0 = qblk * 64;

  // Q fragments (B operand): Q[q0 + qt*32 + l31][kt*16 + hi*8 + j]
  bf16x8 qf[2][4];
#pragma unroll
  for (int qt = 0; qt < 2; ++qt) {
    const bf16* Qb = Qw + (size_t)(b * SS + q0 + qt * 32 + l31) * DD + h * 64 + hi * 8;
#pragma unroll
    for (int kt = 0; kt < 4; ++kt) qf[qt][kt] = *(const bf16x8*)(Qb + kt * 16);
  }
  const bf16* Kg = Kw + (size_t)(b * SS) * DD + h * 64 + hi * 8;
  const bf16* Vg = Vw + (size_t)(b * SS) * DD + h * 64;
  const unsigned* mrow0 = mb + (size_t)(b * SS + q0 + l31) * 32 + w * 8;
  const unsigned* mrow1 = mrow0 + 32 * 32;            // qt=1: +32 q rows

  const int grow = lane >> 3;                         // staging row 0..7
  const int gcol = (lane & 7) * 8;                    // staging col chunk
  const int kvw = w << 8;
  bf16* Vst = sh.v[w];

  f32x16 aco[2][2];
#pragma unroll
  for (int qt = 0; qt < 2; ++qt)
#pragma unroll
    for (int dt = 0; dt < 2; ++dt)
#pragma unroll
      for (int r = 0; r < 16; ++r) aco[qt][dt][r] = 0.f;
  float mx[2] = { -3e38f, -3e38f }, ssum[2] = { 0.f, 0.f };

  for (int t = 0; t < 8; ++t) {
    const int kv0 = kvw + t * 32;
    // (1) V -> LDS, linear coalesced (oldest vmem ops this iter)
#pragma unroll
    for (int i_ = 0; i_ < 4; ++i_)
      gld_lds16(Vg + (size_t)(kv0 + i_ * 8 + grow) * DD + gcol, Vst + i_ * 512);
    // (2) K fragments (A operand) direct from global
    bf16x8 kf[4];
    {
      const bf16* kp = Kg + (size_t)(kv0 + l31) * DD;
#pragma unroll
      for (int kt = 0; kt < 4; ++kt) kf[kt] = *(const bf16x8*)(kp + kt * 16);
    }
    const unsigned mw0 = mrow0[t], mw1 = mrow1[t];

    bf16x8 va[2][2];
    union { bf16x8 v; int q[4]; } pa0[2], pa1[2];
    float psum[2];

#pragma unroll
    for (int qt = 0; qt < 2; ++qt) {
      // swapped QK^T: S[kv][q=l31]
      f32x16 s;
#pragma unroll
      for (int r = 0; r < 16; ++r) s[r] = 0.f;
      __builtin_amdgcn_s_setprio(1);
#pragma unroll
      for (int kt = 0; kt < 4; ++kt) s = mfma32(kf[kt], qf[qt][kt], s);
      __builtin_amdgcn_s_setprio(0);

      const unsigned mw = qt ? mw1 : mw0;
      float p[16];
#pragma unroll
      for (int r = 0; r < 16; ++r) {
        const int pos = (r & 3) + 8 * (r >> 2) + 4 * hi;
        p[r] = ((mw >> pos) & 1) ? s[r] : -1e9f;
      }
      float t0 = fmaxf(p[0], p[1]),  t1 = fmaxf(p[2], p[3]);
      float t2 = fmaxf(p[4], p[5]),  t3 = fmaxf(p[6], p[7]);
      float t4 = fmaxf(p[8], p[9]),  t5 = fmaxf(p[10], p[11]);
      float t6 = fmaxf(p[12], p[13]), t7 = fmaxf(p[14], p[15]);
      float rm = fmaxf(fmaxf(fmaxf(t0, t1), fmaxf(t2, t3)),
                       fmaxf(fmaxf(t4, t5), fmaxf(t6, t7)));
      rm = fmaxf(rm, __shfl_xor(rm, 32));
      if (!__all(rm <= mx[qt] + 8.0f)) {           // defer-max (T13)
        const float mn = fmaxf(mx[qt], rm);
        const float scal = fexp2(mx[qt] - mn);     // per-lane scalar (q = l31)
        mx[qt] = mn; ssum[qt] *= scal;
#pragma unroll
        for (int dt = 0; dt < 2; ++dt)
#pragma unroll
          for (int r = 0; r < 16; ++r) aco[qt][dt][r] *= scal;
      }
#pragma unroll
      for (int r = 0; r < 16; ++r) p[r] = fexp2(p[r] - mx[qt]);
      {
        float a0 = (p[0] + p[1]) + (p[2] + p[3]);
        float a1 = (p[4] + p[5]) + (p[6] + p[7]);
        float a2 = (p[8] + p[9]) + (p[10] + p[11]);
        float a3 = (p[12] + p[13]) + (p[14] + p[15]);
        psum[qt] = (a0 + a1) + (a2 + a3);
      }
      ssum[qt] += psum[qt];
      // pack + XOR-32 routing (verified r7/r9)
      int dpk[8];
#pragma unroll
      for (int i = 0; i < 8; ++i) {
        union { bf16 hh[2]; int v; } u;
        u.hh[0] = (bf16)p[2 * i]; u.hh[1] = (bf16)p[2 * i + 1];
        dpk[i] = u.v;
      }
      const int sa = hi ? dpk[0] : dpk[2], sb = hi ? dpk[1] : dpk[3];
      const int sc_ = hi ? dpk[4] : dpk[6], sd = hi ? dpk[5] : dpk[7];
      const int ra = __shfl_xor(sa, 32), rb = __shfl_xor(sb, 32);
      const int rc = __shfl_xor(sc_, 32), rd = __shfl_xor(sd, 32);
      pa0[qt].q[0] = hi ? ra : dpk[0];  pa0[qt].q[1] = hi ? rb : dpk[1];
      pa0[qt].q[2] = hi ? dpk[2] : ra;  pa0[qt].q[3] = hi ? dpk[3] : rb;
      pa1[qt].q[0] = hi ? rc : dpk[4];  pa1[qt].q[1] = hi ? rd : dpk[5];
      pa1[qt].q[2] = hi ? dpk[6] : rc;  pa1[qt].q[3] = hi ? dpk[7] : rd;

      if (qt == 0) {
        // V staged by now (QK^T + softmax covered the DMA); drain and read
        asm volatile("s_waitcnt vmcnt(0)" ::: "memory");
        __builtin_amdgcn_sched_barrier(0);
#pragma unroll
        for (int dt = 0; dt < 2; ++dt)
#pragma unroll
          for (int s2 = 0; s2 < 2; ++s2) {
            bf16x8 tv;
#pragma unroll
            for (int j = 0; j < 8; ++j)
              tv[j] = Vst[(s2 * 16 + hi * 8 + j) * 64 + dt * 32 + l31];
            va[dt][s2] = tv;
          }
      }
      // PV (O^T): aco[qt][dt] += V^T * P^T
      __builtin_amdgcn_s_setprio(1);
#pragma unroll
      for (int dt = 0; dt < 2; ++dt) {
        aco[qt][dt] = mfma32(va[dt][0], pa0[qt].v, aco[qt][dt]);
        aco[qt][dt] = mfma32(va[dt][1], pa1[qt].v, aco[qt][dt]);
      }
      __builtin_amdgcn_s_setprio(0);
    }
  }

  // ---- merge 4 kv-quarter partials (O^T in LDS) — verbatim r9 ----
#pragma unroll
  for (int qt = 0; qt < 2; ++qt) ssum[qt] += __shfl_xor(ssum[qt], 32);
  __syncthreads();                                  // stage buffers dead
  if (hi == 0) {
#pragma unroll
    for (int qt = 0; qt < 2; ++qt) {
      sh.m.ml[w][0][qt * 32 + l31] = mx[qt];
      sh.m.ml[w][1][qt * 32 + l31] = ssum[qt];
    }
  }
  __syncthreads();
  if (w == 0) {                                     // lane = q (64 q rows)
    const float M0 = sh.m.ml[0][0][lane], M1 = sh.m.ml[1][0][lane];
    const float M2 = sh.m.ml[2][0][lane], M3 = sh.m.ml[3][0][lane];
    const float ms = fmaxf(fmaxf(M0, M1), fmaxf(M2, M3));
    const float ls = sh.m.ml[0][1][lane] * fexp2(M0 - ms)
                   + sh.m.ml[1][1][lane] * fexp2(M1 - ms)
                   + sh.m.ml[2][1][lane] * fexp2(M2 - ms)
                   + sh.m.ml[3][1][lane] * fexp2(M3 - ms);
    sh.m.inv[lane] = 1.0f / ls;
    sh.m.mst[lane] = ms;
  }
  __syncthreads();
  float fown[2];
#pragma unroll
  for (int qt = 0; qt < 2; ++qt)
    fown[qt] = fexp2(sh.m.ml[w][0][qt * 32 + l31] - sh.m.mst[qt * 32 + l31]);
  for (int rd2 = 0; rd2 < 4; ++rd2) {
    if (w == rd2) {
#pragma unroll
      for (int qt = 0; qt < 2; ++qt)
#pragma unroll
        for (int dt = 0; dt < 2; ++dt)
#pragma unroll
          for (int r = 0; r < 16; ++r) {
            const int d = dt * 32 + (r & 3) + 8 * (r >> 2) + 4 * hi;
            const int o = d * 67 + qt * 32 + l31;
            const float val = aco[qt][dt][r] * fown[qt];
            if (rd2 == 0) sh.m.o[o] = val;
            else          sh.m.o[o] += val;
          }
    }
    __syncthreads();
  }
  {
    const int q = tid >> 2, c0 = (tid & 3) * 16;    // o is [d][q] (stride 67)
    const float inv = sh.m.inv[q];
    bf16x8 w0, w1;
#pragma unroll
    for (int j = 0; j < 8; ++j) {
      w0[j] = (bf16)(sh.m.o[(c0 + j) * 67 + q] * inv);
      w1[j] = (bf16)(sh.m.o[(c0 + 8 + j) * 67 + q] * inv);
    }
    bf16* xp = Xw + (size_t)(b * SS + q0 + q) * DD + h * 64 + c0;
    *(bf16x8*)xp = w0;
    *(bf16x8*)(xp + 8) = w1;
  }
}

// ---------------- launch ----------------
extern "C" void kernel_launch(void* const* d_in, const int* in_sizes, int n_in,
                              void* d_out, int out_size, void* d_ws, size_t ws_size,
                              hipStream_t stream) {
  const float* q32 = (const float*)d_in[0];
  const float* k32 = (const float*)d_in[1];
  const float* v32 = (const float*)d_in[2];
  const int* mask = (const int*)d_in[3];
  const float* Wq = (const float*)d_in[4];
  const float* Wk = (const float*)d_in[5];
  const float* Wv = (const float*)d_in[6];
  const float* Wo = (const float*)d_in[7];
  float* out = (float*)d_out;

  const size_t eAct = (size_t)MM * DD;
  const size_t eW = (size_t)DD * DD;

  bf16* Qb = (bf16*)d_ws;
  bf16* Kb = Qb + eAct;
  bf16* Vb = Kb + eAct;
  bf16* Xb = Vb + eAct;
  unsigned* mbits = (unsigned*)(Xb + eAct);
  bf16* cvtBase = (bf16*)(mbits + (size_t)MM * 32);
  bf16* Aq = cvtBase;
  bf16* Ak = Aq + eAct;
  bf16* Av = Ak + eAct;
  bf16* Wqb = Av + eAct;
  bf16* Wkb = Wqb + eW;
  bf16* Wvb = Wkb + eW;
  bf16* Wob = Wvb + eW;
  const size_t need = (size_t)((bf16*)(Wob + eW) - (bf16*)d_ws) * sizeof(bf16);

  k_mask_bits<<<BB * SS, 256, 0, stream>>>(mask, mbits);
  if (ws_size >= need) {
    k_cvt7<<<dim3(2048, 7), 256, 0, stream>>>(q32, k32, v32, Wq, Wk, Wv, Wo,
                                              Aq, Ak, Av, Wqb, Wkb, Wvb, Wob);
    k_gemm_qkv_b16<<<dim3(256, 1, 3), 256, 0, stream>>>(
        Aq, Ak, Av, Wqb, Wkb, Wvb, Qb, Kb, Vb);
    k_attn<<<BB * HH * (SS / 64), 256, 0, stream>>>(Qb, Kb, Vb, mbits, Xb);
    k_gemm_out_b16<<<256, 256, 0, stream>>>(Xb, Wob, out);
  } else {
    k_gemm_qkv<<<dim3((MM / 128) * (DD / 128), 1, 3), 256, 0, stream>>>(
        q32, k32, v32, Wq, Wk, Wv, Qb, Kb, Vb);
    k_attn<<<BB * HH * (SS / 64), 256, 0, stream>>>(Qb, Kb, Vb, mbits, Xb);
    k_gemm_out<<<(MM / 128) * (DD / 128), 256, 0, stream>>>(Xb, Wo, out);
  }
}